// Round 3
// baseline (370.449 us; speedup 1.0000x reference)
//
#include <hip/hip_runtime.h>
#include <stdint.h>

// Problem constants (fixed by the reference)
#define CHARS   10000
#define KPAD    10240   // K padded to multiple of 64
#define HIDDEN  1024
#define OUTPUT  100
#define OPAD    128     // padded output cols for coalesced W2T
#define BATCH   4096
#define MAXLEN  2048

typedef __bf16 bf16_t;
typedef __bf16 bf16x8 __attribute__((ext_vector_type(8)));
typedef __bf16 bf16x4 __attribute__((ext_vector_type(4)));
typedef float  f32x4  __attribute__((ext_vector_type(4)));

// async global->LDS, 16B per lane; LDS dst = wave-uniform base + lane*16 (linear)
__device__ __forceinline__ void gload16(const bf16_t* g, bf16_t* l) {
    __builtin_amdgcn_global_load_lds(
        (__attribute__((address_space(1))) void*)const_cast<bf16_t*>(g),
        (__attribute__((address_space(3))) void*)l, 16, 0, 0);
}

// ---------------------------------------------------------------------------
// Fused prep:
//   blocks [0,2048)    : W1 (HIDDEN x CHARS fp32) -> W1b (HIDDEN x KPAD bf16)
//   blocks [2048,2560) : W2 (OUTPUT x HIDDEN fp32) -> W2T (HIDDEN x OPAD fp32)
//   blocks [2560,4608) : hid[b,h] = b1[h]  (split-K GEMM atomically adds on top)
// ---------------------------------------------------------------------------
__global__ void k_prep(const float* __restrict__ W1, bf16_t* __restrict__ W1b,
                       const float* __restrict__ W2, float* __restrict__ W2T,
                       const float* __restrict__ b1, float* __restrict__ hid) {
    const int bid = blockIdx.x, tid = threadIdx.x;
    if (bid < 2048) {
        const int N4 = (KPAD / 4) * HIDDEN;       // 2.62M float4-groups
        for (int i = bid * 256 + tid; i < N4; i += 2048 * 256) {
            int c4 = i % (KPAD / 4);
            int h  = i / (KPAD / 4);
            bf16x4 o;
            if (c4 * 4 < CHARS) {                 // CHARS % 4 == 0 -> clean split
                f32x4 v = *(const f32x4*)(W1 + (size_t)h * CHARS + (size_t)c4 * 4);
                o[0] = (bf16_t)v[0]; o[1] = (bf16_t)v[1];
                o[2] = (bf16_t)v[2]; o[3] = (bf16_t)v[3];
            } else {
                o[0] = o[1] = o[2] = o[3] = (bf16_t)0.0f;
            }
            *(bf16x4*)(W1b + (size_t)h * KPAD + (size_t)c4 * 4) = o;
        }
    } else if (bid < 2560) {
        int i = (bid - 2048) * 256 + tid;         // 0..131071 = HIDDEN*OPAD
        int o = i & (OPAD - 1), k = i >> 7;
        W2T[i] = (o < OUTPUT) ? W2[(size_t)o * HIDDEN + k] : 0.0f;
    } else {
        const int M4 = BATCH * HIDDEN / 4;
        for (int i = (bid - 2560) * 256 + tid; i < M4; i += 2048 * 256) {
            int h4 = i & (HIDDEN / 4 - 1);
            ((f32x4*)hid)[i] = ((const f32x4*)b1)[h4];
        }
    }
}

// ---------------------------------------------------------------------------
// Per-row histogram: one block per batch row. 40KB LDS uint32 counts.
// Counts are tiny integers -> exact in bf16.
// ---------------------------------------------------------------------------
__global__ void k_hist(const int* __restrict__ words, bf16_t* __restrict__ hist,
                       int rowStart) {
    __shared__ uint32_t h[KPAD];              // 40 KB
    const int tid = threadIdx.x;
    for (int i = tid; i < KPAD; i += 256) h[i] = 0u;
    __syncthreads();
    const int* w = words + (size_t)(rowStart + blockIdx.x) * MAXLEN;
    for (int i = tid; i < MAXLEN; i += 256)
        atomicAdd(&h[w[i]], 1u);
    __syncthreads();
    bf16_t* dst = hist + (size_t)blockIdx.x * KPAD;
    for (int i = tid; i < KPAD; i += 256)
        dst[i] = (bf16_t)(float)h[i];
}

// ---------------------------------------------------------------------------
// 256x256x(BK=64) bf16 MFMA GEMM, 8-phase schedule (m201-class template).
//   R2 fix (isolating the R1 theory): the 12 ds_read_b128 per phase are
//   PINNED pre-barrier via `s_waitcnt lgkmcnt(0)` ("memory" clobber) followed
//   by sched_barrier(0) (rule 18: register-only MFMAs can otherwise hoist
//   past the asm). R0's build (VGPR_Count=108) proved the compiler sank the
//   reads past the barrier and serialized read->wait->MFMA inside the compute
//   window (~2185 cy/phase). With the pin, fragments are live in VGPRs at
//   barrier time and the MFMA cluster runs wait-free.
//   Falsifiable signature: VGPR_Count must rise to >=150.
//   Epilogue: scalar fp32 atomicAdd (gfx950 has no packed-f32 atomic).
// ---------------------------------------------------------------------------
__global__ void __launch_bounds__(512)
k_gemm(const bf16_t* __restrict__ A, const bf16_t* __restrict__ Bt,
       float* __restrict__ hid, int KT, int mtiles) {
    __shared__ __attribute__((aligned(16))) bf16_t As[2][2][128 * 64];  // 64 KB
    __shared__ __attribute__((aligned(16))) bf16_t Bs[2][2][128 * 64];  // 64 KB

    // chunked XCD swizzle (grid % 8 == 0): same (n,s) group contiguous per XCD
    const int nblk = gridDim.x;
    int idx = blockIdx.x;
    if ((nblk & 7) == 0) idx = (idx & 7) * (nblk >> 3) + (idx >> 3);
    const int mt = idx % mtiles;
    const int ns = idx / mtiles;
    const int m0 = mt * 256;
    const int n0 = (ns & 3) * 256;        // HIDDEN/256 == 4
    const int kbeg = (ns >> 2) * KT;      // k-slice start, in 64-wide tiles

    const int tid  = threadIdx.x;
    const int lane = tid & 63;
    const int wave = tid >> 6;            // 0..7
    const int wm64 = (wave >> 2) * 64;    // wave row within 128-row quadrant half
    const int wn32 = (wave & 3) * 32;     // wave col within 128-col quadrant half
    const int l15  = lane & 15;
    const int hi   = lane >> 4;           // k-octet selector
    const int x3   = l15 & 7;             // read-side swizzle XOR

    int arow[4], brow[2], koff[2];
#pragma unroll
    for (int fi = 0; fi < 4; ++fi) arow[fi] = (wm64 + fi * 16 + l15) * 128;
#pragma unroll
    for (int fj = 0; fj < 2; ++fj) brow[fj] = (wn32 + fj * 16 + l15) * 128;
#pragma unroll
    for (int kk = 0; kk < 2; ++kk) koff[kk] = ((((kk << 2) | hi)) ^ x3) * 16;

    // staging map: wave covers 16 rows of a 128x64 half (2 issues x 8 rows);
    // lane -> row (lane>>3), 16B chunk (lane&7)^(lane>>3)  [inverse swizzle]
    const int srow = lane >> 3;
    const int csw8 = ((lane & 7) ^ srow) * 8;
    const bf16_t* Ab = A  + (size_t)(m0 + wave * 16 + srow) * KPAD + csw8;
    const bf16_t* Bb = Bt + (size_t)(n0 + wave * 16 + srow) * KPAD + csw8;
    const int wsl = wave * 2 * 512;       // LDS element offset of this wave's slot

    f32x4 acc[2][2][4][2] = {};

#define STAGE(SB, SOP, SH, KTILE_) do {                                        \
    int kte_ = (KTILE_); if (kte_ >= KT) kte_ = 0; /* tail clamp */            \
    const size_t kc_ = (size_t)(kbeg + kte_) * 64;                             \
    const bf16_t* gb_ = (SOP) ? Bb : Ab;                                       \
    bf16_t* lb_ = ((SOP) ? &Bs[SB][SH][0] : &As[SB][SH][0]) + wsl;             \
    gload16(gb_ + (size_t)((SH) * 128)     * KPAD + kc_, lb_);                 \
    gload16(gb_ + (size_t)((SH) * 128 + 8) * KPAD + kc_, lb_ + 512);           \
} while (0)

#define PHASE(PB, QI, QJ, SB, SOP, SH, SOFF, DOVM) do {                        \
    STAGE(SB, SOP, SH, kt + (SOFF));                                           \
    bf16x8 af_[2][4], bv_[2][2];                                               \
    const char* Aq_ = (const char*)&As[PB][QI][0];                             \
    const char* Bq_ = (const char*)&Bs[PB][QJ][0];                             \
    _Pragma("unroll") for (int kk = 0; kk < 2; ++kk) {                         \
        _Pragma("unroll") for (int fi = 0; fi < 4; ++fi)                       \
            af_[kk][fi] = *(const bf16x8*)(Aq_ + arow[fi] + koff[kk]);         \
        _Pragma("unroll") for (int fj = 0; fj < 2; ++fj)                       \
            bv_[kk][fj] = *(const bf16x8*)(Bq_ + brow[fj] + koff[kk]);         \
    }                                                                          \
    /* pin reads pre-barrier: loads cannot sink past a memory asm; the      */ \
    /* sched_barrier stops MFMAs hoisting above it (rule 18). Fragments     */ \
    /* complete AND stay live in VGPRs; MFMA cluster below runs wait-free.  */ \
    asm volatile("s_waitcnt lgkmcnt(0)" ::: "memory");                         \
    __builtin_amdgcn_sched_barrier(0);                                         \
    if (DOVM) asm volatile("s_waitcnt vmcnt(4)" ::: "memory");                 \
    __builtin_amdgcn_s_barrier();                                              \
    __builtin_amdgcn_s_setprio(1);                                             \
    _Pragma("unroll") for (int kk = 0; kk < 2; ++kk)                           \
        _Pragma("unroll") for (int fi = 0; fi < 4; ++fi)                       \
            _Pragma("unroll") for (int fj = 0; fj < 2; ++fj)                   \
                acc[QI][QJ][fi][fj] = __builtin_amdgcn_mfma_f32_16x16x32_bf16( \
                    af_[kk][fi], bv_[kk][fj], acc[QI][QJ][fi][fj], 0, 0, 0);   \
    __builtin_amdgcn_s_setprio(0);                                             \
    __builtin_amdgcn_s_barrier();                                              \
} while (0)

    // prologue: tile0 complete into buf0, tile1 {B0,A0} into buf1
    STAGE(0, 0, 0, 0);
    STAGE(0, 1, 0, 0);
    STAGE(0, 0, 1, 0);
    STAGE(0, 1, 1, 0);
    STAGE(1, 1, 0, 1);
    STAGE(1, 0, 0, 1);
    asm volatile("s_waitcnt vmcnt(4)" ::: "memory");   // tile0 landed
    __builtin_amdgcn_s_barrier();

    for (int kt = 0; kt < KT; kt += 2) {
        //     buf qi qj | sbuf sop shalf | +kt | vm
        PHASE(0, 0, 0,    1, 0, 1,          1,   0);  // stage buf1.A1 (t+1)
        PHASE(0, 1, 0,    1, 1, 1,          1,   0);  // stage buf1.B1 (t+1)
        PHASE(0, 0, 1,    0, 1, 0,          2,   0);  // stage buf0.B0 (t+2)
        PHASE(0, 1, 1,    0, 0, 0,          2,   1);  // stage buf0.A0 (t+2), vmcnt
        PHASE(1, 0, 0,    0, 0, 1,          2,   0);  // stage buf0.A1 (t+2)
        PHASE(1, 1, 0,    0, 1, 1,          2,   0);  // stage buf0.B1 (t+2)
        PHASE(1, 0, 1,    1, 1, 0,          3,   0);  // stage buf1.B0 (t+3)
        PHASE(1, 1, 1,    1, 0, 0,          3,   1);  // stage buf1.A0 (t+3), vmcnt
    }
#undef PHASE
#undef STAGE

    // epilogue: C/D layout col=lane&15, row=(lane>>4)*4+reg  [guide §3, m89]
    const int er = hi * 4;
#pragma unroll
    for (int qi = 0; qi < 2; ++qi)
#pragma unroll
    for (int qj = 0; qj < 2; ++qj)
#pragma unroll
    for (int fi = 0; fi < 4; ++fi)
#pragma unroll
    for (int fj = 0; fj < 2; ++fj) {
        float* dst = hid + (size_t)(m0 + qi * 128 + wm64 + fi * 16 + er) * HIDDEN
                         + (n0 + qj * 128 + wn32 + fj * 16 + l15);
#pragma unroll
        for (int r = 0; r < 4; ++r)
            atomicAdd(dst + (size_t)r * HIDDEN, acc[qi][qj][fi][fj][r]);
    }
}

// ---------------------------------------------------------------------------
// out[b,o] = sum_k hid[b,k] * W2T[k,o] + b2[o]
// ---------------------------------------------------------------------------
__global__ void k_out(const float* __restrict__ hid, const float* __restrict__ W2T,
                      const float* __restrict__ b2, float* __restrict__ out) {
    const int tid = threadIdx.x;
    const int o4  = (tid & 31) * 4;       // 0,4,...,124
    const int rs  = tid >> 5;             // 0..7
    const int row = blockIdx.x * 8 + rs;
    const float* hrow = hid + (size_t)row * HIDDEN;
    f32x4 acc = {0.f, 0.f, 0.f, 0.f};
    for (int k0 = 0; k0 < HIDDEN; k0 += 4) {
        f32x4 hv = *(const f32x4*)(hrow + k0);
#pragma unroll
        for (int q = 0; q < 4; ++q) {
            f32x4 wv = *(const f32x4*)(W2T + (size_t)(k0 + q) * OPAD + o4);
            acc += hv[q] * wv;
        }
    }
    if (o4 < OUTPUT) {
        float* op = out + (size_t)row * OUTPUT + o4;
#pragma unroll
        for (int q = 0; q < 4; ++q)
            op[q] = acc[q] + b2[o4 + q];
    }
}

// ---------------------------------------------------------------------------
// split-K: largest S with grid = mtiles*4*S <= 256 (1 block/CU at 128KB LDS);
// all candidates divide 160 with even quotient (template needs even KT).
// ---------------------------------------------------------------------------
static inline int pick_S(int mtiles) {
    const int cands[10] = {80, 40, 20, 16, 10, 8, 5, 4, 2, 1};
    for (int i = 0; i < 10; ++i)
        if (mtiles * 4 * cands[i] <= 256) return cands[i];
    return 1;
}

extern "C" void kernel_launch(void* const* d_in, const int* in_sizes, int n_in,
                              void* d_out, int out_size, void* d_ws, size_t ws_size,
                              hipStream_t stream) {
    (void)in_sizes; (void)n_in; (void)out_size;
    const int*   words = (const int*)d_in[0];
    const float* W1    = (const float*)d_in[1];
    const float* b1    = (const float*)d_in[2];
    const float* W2    = (const float*)d_in[3];
    const float* b2    = (const float*)d_in[4];
    float* out = (float*)d_out;

    // workspace layout
    char* ws = (char*)d_ws;
    size_t off = 0;
    bf16_t* W1b  = (bf16_t*)(ws + off); off += (size_t)HIDDEN * KPAD * sizeof(bf16_t); // 21.0 MB
    float*  hid  = (float*) (ws + off); off += (size_t)BATCH * HIDDEN * sizeof(float); // 16.8 MB
    float*  W2T  = (float*) (ws + off); off += (size_t)HIDDEN * OPAD * sizeof(float);  // 0.5 MB
    bf16_t* histC = (bf16_t*)(ws + off);
    size_t rem = (ws_size > off) ? (ws_size - off) : 0;
    int chunkRows = (int)(rem / ((size_t)KPAD * sizeof(bf16_t)));
    chunkRows = (chunkRows / 256) * 256;
    if (chunkRows > BATCH) chunkRows = BATCH;
    if (chunkRows < 256)   chunkRows = 256;

    k_prep<<<dim3(4608), dim3(256), 0, stream>>>(W1, W1b, W2, W2T, b1, hid);

    for (int r0 = 0; r0 < BATCH; r0 += chunkRows) {
        int rows = BATCH - r0;
        if (rows > chunkRows) rows = chunkRows;
        k_hist<<<dim3(rows), dim3(256), 0, stream>>>(words, histC, r0);
        int mtiles = rows / 256;
        int S = pick_S(mtiles);
        int KT = (KPAD / 64) / S;
        k_gemm<<<dim3(mtiles * 4 * S), dim3(512), 0, stream>>>(
            histC, W1b, hid + (size_t)r0 * HIDDEN, KT, mtiles);
    }

    k_out<<<dim3(BATCH / 8), dim3(256), 0, stream>>>(hid, W2T, b2, out);
}

// Round 4
// 321.283 us; speedup vs baseline: 1.1530x; 1.1530x over previous
//
#include <hip/hip_runtime.h>
#include <stdint.h>

// Problem constants (fixed by the reference)
#define CHARS   10000
#define KPAD    10240   // K padded to multiple of 64
#define HIDDEN  1024
#define OUTPUT  100
#define OPAD    128     // padded output cols for coalesced W2T
#define BATCH   4096
#define MAXLEN  2048

typedef __bf16 bf16_t;
typedef __bf16 bf16x8 __attribute__((ext_vector_type(8)));
typedef __bf16 bf16x4 __attribute__((ext_vector_type(4)));
typedef float  f32x4  __attribute__((ext_vector_type(4)));
typedef uint32_t u32x4 __attribute__((ext_vector_type(4)));

// async global->LDS, 16B per lane; LDS dst = wave-uniform base + lane*16 (linear)
__device__ __forceinline__ void gload16(const bf16_t* g, bf16_t* l) {
    __builtin_amdgcn_global_load_lds(
        (__attribute__((address_space(1))) void*)const_cast<bf16_t*>(g),
        (__attribute__((address_space(3))) void*)l, 16, 0, 0);
}

// ---------------------------------------------------------------------------
// Fused prep:
//   blocks [0,2048)    : W1 (HIDDEN x CHARS fp32) -> W1b (HIDDEN x KPAD bf16)
//   blocks [2048,2560) : W2 (OUTPUT x HIDDEN fp32) -> W2T (HIDDEN x OPAD fp32)
//   blocks [2560,4608) : hid[b,h] = b1[h]  (split-K GEMM atomically adds on top)
// ---------------------------------------------------------------------------
__global__ void k_prep(const float* __restrict__ W1, bf16_t* __restrict__ W1b,
                       const float* __restrict__ W2, float* __restrict__ W2T,
                       const float* __restrict__ b1, float* __restrict__ hid) {
    const int bid = blockIdx.x, tid = threadIdx.x;
    if (bid < 2048) {
        const int N4 = (KPAD / 4) * HIDDEN;       // 2.62M float4-groups
        for (int i = bid * 256 + tid; i < N4; i += 2048 * 256) {
            int c4 = i % (KPAD / 4);
            int h  = i / (KPAD / 4);
            bf16x4 o;
            if (c4 * 4 < CHARS) {                 // CHARS % 4 == 0 -> clean split
                f32x4 v = *(const f32x4*)(W1 + (size_t)h * CHARS + (size_t)c4 * 4);
                o[0] = (bf16_t)v[0]; o[1] = (bf16_t)v[1];
                o[2] = (bf16_t)v[2]; o[3] = (bf16_t)v[3];
            } else {
                o[0] = o[1] = o[2] = o[3] = (bf16_t)0.0f;
            }
            *(bf16x4*)(W1b + (size_t)h * KPAD + (size_t)c4 * 4) = o;
        }
    } else if (bid < 2560) {
        int i = (bid - 2048) * 256 + tid;         // 0..131071 = HIDDEN*OPAD
        int o = i & (OPAD - 1), k = i >> 7;
        W2T[i] = (o < OUTPUT) ? W2[(size_t)o * HIDDEN + k] : 0.0f;
    } else {
        const int M4 = BATCH * HIDDEN / 4;
        for (int i = (bid - 2560) * 256 + tid; i < M4; i += 2048 * 256) {
            int h4 = i & (HIDDEN / 4 - 1);
            ((f32x4*)hid)[i] = ((const f32x4*)b1)[h4];
        }
    }
}

// ---------------------------------------------------------------------------
// Per-row histogram: one block per batch row. 40KB LDS uint32 counts.
// Counts are tiny integers -> exact in bf16. Vectorized: u32x4 zero-init,
// int4 word loads, bf16x8 output stores (G13).
// ---------------------------------------------------------------------------
__global__ void k_hist(const int* __restrict__ words, bf16_t* __restrict__ hist,
                       int rowStart) {
    __shared__ uint32_t h[KPAD];              // 40 KB
    const int tid = threadIdx.x;
#pragma unroll
    for (int i = 0; i < KPAD / 4 / 256; ++i)  // 10 iters
        *(u32x4*)(h + (i * 256 + tid) * 4) = (u32x4){0u, 0u, 0u, 0u};
    __syncthreads();
    const int* w = words + (size_t)(rowStart + blockIdx.x) * MAXLEN;
#pragma unroll
    for (int i = 0; i < MAXLEN / 4 / 256; ++i) {  // 2 iters
        int4 t4 = *(const int4*)(w + (i * 256 + tid) * 4);
        atomicAdd(&h[t4.x], 1u); atomicAdd(&h[t4.y], 1u);
        atomicAdd(&h[t4.z], 1u); atomicAdd(&h[t4.w], 1u);
    }
    __syncthreads();
    bf16_t* dst = hist + (size_t)blockIdx.x * KPAD;
#pragma unroll
    for (int i = 0; i < KPAD / 8 / 256; ++i) {    // 5 iters
        int j = (i * 256 + tid) * 8;
        bf16x8 o;
#pragma unroll
        for (int q = 0; q < 8; ++q) o[q] = (bf16_t)(float)h[j + q];
        *(bf16x8*)(dst + j) = o;
    }
}

// ---------------------------------------------------------------------------
// 256x256x(BK=64) bf16 MFMA GEMM, 8-phase schedule (m201-class template).
//   R3 restructure: fragment-REUSE phase order. Per K-tile the 4 quadrant
//   phases load {A0+B0 (12 reads), A1 (8), B1 (4), none (0)} and hold
//   fragments in registers across phases (barrier memory-clobbers force
//   liveness) -> per-wave LDS reads per K-tile drop 48 -> 24 (the minimum).
//   R0/R2 measured the amplified version LDS-read-bound (MfmaUtil 21-23%,
//   384KB LDS reads per K-tile per CU vs MFMA's ~2048 cy).
//   lgkmcnt(0) moved AFTER the pre-MFMA barrier (m201 placement; R2's
//   pre-barrier pin serialized last-wave read latency into the rendezvous),
//   followed by sched_barrier(0) (rule 18). vmcnt(4) at phases 4/8 only.
//   Stage ledger re-verified for the new read times:
//     ph1..8 stage {b1.A1,b1.B1,b0.B0,b0.A0,b0.A1,b0.B1,b1.B0,b1.A0}
//     (t+1/t+2/t+3); region last-LDS-reads now {A0:ph1, B0:ph1, A1:ph2,
//     B1:ph3} per buf -> every stage still lands after its region's last
//     read, every half still lands (via vmcnt(4)) before its first read.
//   Split-K over slices -> fp32 atomicAdd into b1-preinitialized hid.
// ---------------------------------------------------------------------------
__global__ void __launch_bounds__(512)
k_gemm(const bf16_t* __restrict__ A, const bf16_t* __restrict__ Bt,
       float* __restrict__ hid, int KT, int mtiles) {
    __shared__ __attribute__((aligned(16))) bf16_t As[2][2][128 * 64];  // 64 KB
    __shared__ __attribute__((aligned(16))) bf16_t Bs[2][2][128 * 64];  // 64 KB

    // chunked XCD swizzle (grid % 8 == 0): same (n,s) group contiguous per XCD
    const int nblk = gridDim.x;
    int idx = blockIdx.x;
    if ((nblk & 7) == 0) idx = (idx & 7) * (nblk >> 3) + (idx >> 3);
    const int mt = idx % mtiles;
    const int ns = idx / mtiles;
    const int m0 = mt * 256;
    const int n0 = (ns & 3) * 256;        // HIDDEN/256 == 4
    const int kbeg = (ns >> 2) * KT;      // k-slice start, in 64-wide tiles

    const int tid  = threadIdx.x;
    const int lane = tid & 63;
    const int wave = tid >> 6;            // 0..7
    const int wm64 = (wave >> 2) * 64;    // wave row within 128-row quadrant half
    const int wn32 = (wave & 3) * 32;     // wave col within 128-col quadrant half
    const int l15  = lane & 15;
    const int hi   = lane >> 4;           // k-octet selector
    const int x3   = l15 & 7;             // read-side swizzle XOR

    int arow[4], brow[2], koff[2];
#pragma unroll
    for (int fi = 0; fi < 4; ++fi) arow[fi] = (wm64 + fi * 16 + l15) * 128;
#pragma unroll
    for (int fj = 0; fj < 2; ++fj) brow[fj] = (wn32 + fj * 16 + l15) * 128;
#pragma unroll
    for (int kk = 0; kk < 2; ++kk) koff[kk] = ((((kk << 2) | hi)) ^ x3) * 16;

    // staging map: wave covers 16 rows of a 128x64 half (2 issues x 8 rows);
    // lane -> row (lane>>3), 16B chunk (lane&7)^(lane>>3)  [inverse swizzle]
    const int srow = lane >> 3;
    const int csw8 = ((lane & 7) ^ srow) * 8;
    const bf16_t* Ab = A  + (size_t)(m0 + wave * 16 + srow) * KPAD + csw8;
    const bf16_t* Bb = Bt + (size_t)(n0 + wave * 16 + srow) * KPAD + csw8;
    const int wsl = wave * 2 * 512;       // LDS element offset of this wave's slot

    f32x4 acc[2][2][4][2] = {};
    bf16x8 fa0[2][4], fa1[2][4], fb0[2][2], fb1[2][2];

#define STAGE(SB, SOP, SH, KTILE_) do {                                        \
    int kte_ = (KTILE_); if (kte_ >= KT) kte_ = 0; /* tail clamp */            \
    const size_t kc_ = (size_t)(kbeg + kte_) * 64;                             \
    const bf16_t* gb_ = (SOP) ? Bb : Ab;                                       \
    bf16_t* lb_ = ((SOP) ? &Bs[SB][SH][0] : &As[SB][SH][0]) + wsl;             \
    gload16(gb_ + (size_t)((SH) * 128)     * KPAD + kc_, lb_);                 \
    gload16(gb_ + (size_t)((SH) * 128 + 8) * KPAD + kc_, lb_ + 512);           \
} while (0)

#define LOADA(DST, PB, HALF) do {                                              \
    const char* p_ = (const char*)&As[PB][HALF][0];                            \
    _Pragma("unroll") for (int kk = 0; kk < 2; ++kk)                           \
        _Pragma("unroll") for (int fi = 0; fi < 4; ++fi)                       \
            DST[kk][fi] = *(const bf16x8*)(p_ + arow[fi] + koff[kk]);          \
} while (0)

#define LOADB(DST, PB, HALF) do {                                              \
    const char* p_ = (const char*)&Bs[PB][HALF][0];                            \
    _Pragma("unroll") for (int kk = 0; kk < 2; ++kk)                           \
        _Pragma("unroll") for (int fj = 0; fj < 2; ++fj)                       \
            DST[kk][fj] = *(const bf16x8*)(p_ + brow[fj] + koff[kk]);          \
} while (0)

// barrier -> wait -> pinned MFMA cluster -> barrier
#define WAITL() do {                                                           \
    __builtin_amdgcn_s_barrier();                                              \
    asm volatile("s_waitcnt lgkmcnt(0)" ::: "memory");                         \
    __builtin_amdgcn_sched_barrier(0);                                         \
} while (0)

#define WAITLV() do {                                                          \
    __builtin_amdgcn_s_barrier();                                              \
    asm volatile("s_waitcnt lgkmcnt(0)" ::: "memory");                         \
    asm volatile("s_waitcnt vmcnt(4)" ::: "memory");                           \
    __builtin_amdgcn_sched_barrier(0);                                         \
} while (0)

#define MM(QI, QJ, FA, FB) do {                                                \
    __builtin_amdgcn_s_setprio(1);                                             \
    _Pragma("unroll") for (int kk = 0; kk < 2; ++kk)                           \
        _Pragma("unroll") for (int fi = 0; fi < 4; ++fi)                       \
            _Pragma("unroll") for (int fj = 0; fj < 2; ++fj)                   \
                acc[QI][QJ][fi][fj] = __builtin_amdgcn_mfma_f32_16x16x32_bf16( \
                    FA[kk][fi], FB[kk][fj], acc[QI][QJ][fi][fj], 0, 0, 0);     \
    __builtin_amdgcn_s_setprio(0);                                             \
    __builtin_amdgcn_s_barrier();                                              \
} while (0)

    // prologue: tile0 complete into buf0, tile1 {B0,A0} into buf1
    STAGE(0, 0, 0, 0);
    STAGE(0, 1, 0, 0);
    STAGE(0, 0, 1, 0);
    STAGE(0, 1, 1, 0);
    STAGE(1, 1, 0, 1);
    STAGE(1, 0, 0, 1);
    asm volatile("s_waitcnt vmcnt(4)" ::: "memory");   // tile0 landed
    __builtin_amdgcn_s_barrier();

    for (int kt = 0; kt < KT; kt += 2) {
        // ---- tile kt (buf0): loads 12 / 8 / 4 / 0, frags held across phases
        STAGE(1, 0, 1, kt + 1);  LOADA(fa0, 0, 0); LOADB(fb0, 0, 0);
        WAITL();  MM(0, 0, fa0, fb0);
        STAGE(1, 1, 1, kt + 1);  LOADA(fa1, 0, 1);
        WAITL();  MM(1, 0, fa1, fb0);
        STAGE(0, 1, 0, kt + 2);  LOADB(fb1, 0, 1);
        WAITL();  MM(0, 1, fa0, fb1);
        STAGE(0, 0, 0, kt + 2);
        WAITLV(); MM(1, 1, fa1, fb1);
        // ---- tile kt+1 (buf1)
        STAGE(0, 0, 1, kt + 2);  LOADA(fa0, 1, 0); LOADB(fb0, 1, 0);
        WAITL();  MM(0, 0, fa0, fb0);
        STAGE(0, 1, 1, kt + 2);  LOADA(fa1, 1, 1);
        WAITL();  MM(1, 0, fa1, fb0);
        STAGE(1, 1, 0, kt + 3);  LOADB(fb1, 1, 1);
        WAITL();  MM(0, 1, fa0, fb1);
        STAGE(1, 0, 0, kt + 3);
        WAITLV(); MM(1, 1, fa1, fb1);
    }
#undef MM
#undef WAITLV
#undef WAITL
#undef LOADB
#undef LOADA
#undef STAGE

    // epilogue: C/D layout col=lane&15, row=(lane>>4)*4+reg  [guide §3, m89]
    const int er = hi * 4;
#pragma unroll
    for (int qi = 0; qi < 2; ++qi)
#pragma unroll
    for (int qj = 0; qj < 2; ++qj)
#pragma unroll
    for (int fi = 0; fi < 4; ++fi)
#pragma unroll
    for (int fj = 0; fj < 2; ++fj) {
        float* dst = hid + (size_t)(m0 + qi * 128 + wm64 + fi * 16 + er) * HIDDEN
                         + (n0 + qj * 128 + wn32 + fj * 16 + l15);
#pragma unroll
        for (int r = 0; r < 4; ++r)
            atomicAdd(dst + (size_t)r * HIDDEN, acc[qi][qj][fi][fj][r]);
    }
}

// ---------------------------------------------------------------------------
// out[b,o] = sum_k hid[b,k] * W2T[k,o] + b2[o]
// ---------------------------------------------------------------------------
__global__ void k_out(const float* __restrict__ hid, const float* __restrict__ W2T,
                      const float* __restrict__ b2, float* __restrict__ out) {
    const int tid = threadIdx.x;
    const int o4  = (tid & 31) * 4;       // 0,4,...,124
    const int rs  = tid >> 5;             // 0..7
    const int row = blockIdx.x * 8 + rs;
    const float* hrow = hid + (size_t)row * HIDDEN;
    f32x4 acc = {0.f, 0.f, 0.f, 0.f};
    for (int k0 = 0; k0 < HIDDEN; k0 += 4) {
        f32x4 hv = *(const f32x4*)(hrow + k0);
#pragma unroll
        for (int q = 0; q < 4; ++q) {
            f32x4 wv = *(const f32x4*)(W2T + (size_t)(k0 + q) * OPAD + o4);
            acc += hv[q] * wv;
        }
    }
    if (o4 < OUTPUT) {
        float* op = out + (size_t)row * OUTPUT + o4;
#pragma unroll
        for (int q = 0; q < 4; ++q)
            op[q] = acc[q] + b2[o4 + q];
    }
}

// ---------------------------------------------------------------------------
// split-K: largest S with grid = mtiles*4*S <= 256 (1 block/CU at 128KB LDS);
// all candidates divide 160 with even quotient (template needs even KT).
// ---------------------------------------------------------------------------
static inline int pick_S(int mtiles) {
    const int cands[10] = {80, 40, 20, 16, 10, 8, 5, 4, 2, 1};
    for (int i = 0; i < 10; ++i)
        if (mtiles * 4 * cands[i] <= 256) return cands[i];
    return 1;
}

extern "C" void kernel_launch(void* const* d_in, const int* in_sizes, int n_in,
                              void* d_out, int out_size, void* d_ws, size_t ws_size,
                              hipStream_t stream) {
    (void)in_sizes; (void)n_in; (void)out_size;
    const int*   words = (const int*)d_in[0];
    const float* W1    = (const float*)d_in[1];
    const float* b1    = (const float*)d_in[2];
    const float* W2    = (const float*)d_in[3];
    const float* b2    = (const float*)d_in[4];
    float* out = (float*)d_out;

    // workspace layout
    char* ws = (char*)d_ws;
    size_t off = 0;
    bf16_t* W1b  = (bf16_t*)(ws + off); off += (size_t)HIDDEN * KPAD * sizeof(bf16_t); // 21.0 MB
    float*  hid  = (float*) (ws + off); off += (size_t)BATCH * HIDDEN * sizeof(float); // 16.8 MB
    float*  W2T  = (float*) (ws + off); off += (size_t)HIDDEN * OPAD * sizeof(float);  // 0.5 MB
    bf16_t* histC = (bf16_t*)(ws + off);
    size_t rem = (ws_size > off) ? (ws_size - off) : 0;
    int chunkRows = (int)(rem / ((size_t)KPAD * sizeof(bf16_t)));
    chunkRows = (chunkRows / 256) * 256;
    if (chunkRows > BATCH) chunkRows = BATCH;
    if (chunkRows < 256)   chunkRows = 256;

    k_prep<<<dim3(4608), dim3(256), 0, stream>>>(W1, W1b, W2, W2T, b1, hid);

    for (int r0 = 0; r0 < BATCH; r0 += chunkRows) {
        int rows = BATCH - r0;
        if (rows > chunkRows) rows = chunkRows;
        k_hist<<<dim3(rows), dim3(256), 0, stream>>>(words, histC, r0);
        int mtiles = rows / 256;
        int S = pick_S(mtiles);
        int KT = (KPAD / 64) / S;
        k_gemm<<<dim3(mtiles * 4 * S), dim3(512), 0, stream>>>(
            histC, W1b, hid + (size_t)r0 * HIDDEN, KT, mtiles);
    }

    k_out<<<dim3(BATCH / 8), dim3(256), 0, stream>>>(hid, W2T, b2, out);
}